// Round 7
// baseline (209.384 us; speedup 1.0000x reference)
//
#include <hip/hip_runtime.h>
#include <stdint.h>
#include <math.h>

#define ROWLEN 84
#define F4PR 21              // float4s per row (84 floats)
#define CANDCAP (1u << 20)   // candidate buffer cap (8 MB)

__device__ __forceinline__ uint32_t map_f(float f) {
    uint32_t u = __float_as_uint(f);
    return (u & 0x80000000u) ? ~u : (u | 0x80000000u);
}
__device__ __forceinline__ float unmap_f(uint32_t u) {
    uint32_t b = (u & 0x80000000u) ? (u & 0x7FFFFFFFu) : ~u;
    return __uint_as_float(b);
}

// Parallel bin find over hist[nbins]: bin b with suffix(b+1..) < target <= suffix(b..).
// 256 threads; returns identical (bin, count-strictly-above) to all. hist may be global or LDS.
__device__ void find_parallel(const uint32_t* hist, int nbins, uint32_t target,
                              uint32_t* s, uint32_t* sc2, uint32_t* outBin, uint32_t* outAbove) {
    int tid = threadIdx.x;
    int chunks = nbins / 256;
    int base = tid * chunks;
    uint32_t part = 0;
    for (int i = 0; i < chunks; ++i) part += hist[base + i];
    s[tid] = part;
    __syncthreads();
    for (int off = 1; off < 256; off <<= 1) {  // suffix sums
        uint32_t v = (tid + off < 256) ? s[tid + off] : 0u;
        __syncthreads();
        s[tid] += v;
        __syncthreads();
    }
    uint32_t above_next = (tid < 255) ? s[tid + 1] : 0u;
    bool mine = (s[tid] >= target) && (above_next < target);  // exactly one thread
    if (mine) { sc2[0] = (uint32_t)tid; sc2[1] = above_next; }
    __syncthreads();
    uint32_t c = sc2[0], above = sc2[1];
    if (tid == 0) {  // <= chunks serial reads within the winning chunk
        uint32_t acc = above;
        int b = (int)c * chunks + chunks - 1;
        for (;; --b) {
            uint32_t hb = hist[b];
            if (acc + hb >= target) break;
            acc += hb;
        }
        sc2[0] = (uint32_t)b;
        sc2[1] = acc;
    }
    __syncthreads();
    *outBin = sc2[0];
    *outAbove = sc2[1];
}

// Pass 1 (barrier-free streaming): one wave handles 3 rows (63 float4s = 1008 B contiguous).
// lane l -> row l/21, chunk l%21; chunk 0 = boxes (masked). Row max via 5 masked shfl steps
// (idempotent max over the 21-lane group). 2 triples per iteration for MLP.
// Also zeroes *out and candCnt (used >=2 dispatches later; race-free).
__global__ __launch_bounds__(256) void k_score_hist(const float* __restrict__ pred,
                                                    uint32_t* __restrict__ scores,
                                                    uint32_t* __restrict__ gH1,
                                                    uint32_t* __restrict__ candCnt,
                                                    float* __restrict__ out, int n) {
    __shared__ uint32_t h[1024];
    int tid = threadIdx.x;
    if (blockIdx.x == 0 && tid == 0) { *out = 0.f; *candCnt = 0u; }
    for (int i = tid; i < 1024; i += 256) h[i] = 0;
    __syncthreads();
    const float4* pf4 = (const float4*)pred;
    size_t total_f4 = (size_t)n * F4PR;
    int lane = tid & 63;
    int wv = (blockIdx.x * 256 + tid) >> 6;   // global wave id
    int nw = gridDim.x * 4;                   // total waves
    int g = lane / 21;                        // row-in-triple (3 = idle lane 63)
    int rel = lane - g * 21;                  // 0..20; 0 = box chunk
    bool lv = (lane < 63);
    int ntrip = (n + 2) / 3;
    const int OFFS[5] = {10, 5, 3, 2, 1};
    for (int t0 = wv * 2; t0 < ntrip; t0 += nw * 2) {
        float mA = -INFINITY, mB = -INFINITY;
        size_t iA = (size_t)t0 * 63 + lane;   // == rowA*21 + rel
        size_t iB = iA + 63;
        if (lv && rel != 0 && iA < total_f4) {
            float4 v = pf4[iA];
            mA = fmaxf(fmaxf(v.x, v.y), fmaxf(v.z, v.w));
        }
        if (lv && rel != 0 && iB < total_f4) {
            float4 v = pf4[iB];
            mB = fmaxf(fmaxf(v.x, v.y), fmaxf(v.z, v.w));
        }
#pragma unroll
        for (int k = 0; k < 5; ++k) {
            int off = OFFS[k];
            float oA = __shfl(mA, lane + off);
            float oB = __shfl(mB, lane + off);
            if (rel + off <= 20) { mA = fmaxf(mA, oA); mB = fmaxf(mB, oB); }
        }
        if (rel == 1) {  // holds max over rel 1..20 of its row
            int rA = t0 * 3 + g;
            if (rA < n) {
                uint32_t u = map_f(mA);
                scores[rA] = u;
                atomicAdd(&h[u >> 22], 1u);
            }
            int rB = rA + 3;
            if (rB < n) {
                uint32_t u = map_f(mB);
                scores[rB] = u;
                atomicAdd(&h[u >> 22], 1u);
            }
        }
    }
    __syncthreads();
    for (int i = tid; i < 1024; i += 256)
        if (h[i]) atomicAdd(&gH1[i], h[i]);
}

// Pass 2: every block computes find1(gH1) itself; block 0 persists bin1/chi1.
// Level-2 histogram (bits [21:11]) of keys whose top 10 bits == bin1. uint4 scan.
__global__ void k_hist2f(const uint32_t* __restrict__ scores, const uint32_t* __restrict__ gH1,
                         uint32_t* __restrict__ gH2, uint32_t* __restrict__ sres,
                         int n, uint32_t K) {
    __shared__ uint32_t h[2048];
    __shared__ uint32_t s[256];
    __shared__ uint32_t sc2[2];
    for (int i = threadIdx.x; i < 2048; i += 256) h[i] = 0;
    uint32_t bin1, chi1;
    find_parallel(gH1, 1024, K, s, sc2, &bin1, &chi1);
    if (blockIdx.x == 0 && threadIdx.x == 0) { sres[0] = bin1; sres[1] = chi1; }
    int gid = blockIdx.x * 256 + threadIdx.x;
    int stride = gridDim.x * 256;
    const uint4* s4 = (const uint4*)scores;
    int n4 = n >> 2;
    for (int i = gid; i < n4; i += stride) {
        uint4 uu = s4[i];
        if ((uu.x >> 22) == bin1) atomicAdd(&h[(uu.x >> 11) & 0x7FFu], 1u);
        if ((uu.y >> 22) == bin1) atomicAdd(&h[(uu.y >> 11) & 0x7FFu], 1u);
        if ((uu.z >> 22) == bin1) atomicAdd(&h[(uu.z >> 11) & 0x7FFu], 1u);
        if ((uu.w >> 22) == bin1) atomicAdd(&h[(uu.w >> 11) & 0x7FFu], 1u);
    }
    for (int r = n4 * 4 + gid; r < n; r += stride) {
        uint32_t u = scores[r];
        if ((u >> 22) == bin1) atomicAdd(&h[(u >> 11) & 0x7FFu], 1u);
    }
    __syncthreads();
    for (int i = threadIdx.x; i < 2048; i += 256)
        if (h[i]) atomicAdd(&gH2[i], h[i]);
}

// Pass 3: find2(gH2) -> 21-bit threshold bucket t21. Sum definitely-selected rows
// ((u>>11) > t21, or u >= CONF when bucket below CONF); compact bucket-resident
// candidates (row,key) for the final refinement. Block 0 persists t21/chiTot/m'.
__global__ void k_select2(const float* __restrict__ pred, const uint32_t* __restrict__ scores,
                          const uint32_t* __restrict__ gH2, uint32_t* __restrict__ sres,
                          uint32_t* __restrict__ candCnt, uint2* __restrict__ candBuf,
                          float* __restrict__ out, int n, uint32_t K) {
    __shared__ uint32_t s[256];
    __shared__ uint32_t sc2[2];
    __shared__ float wsum[4];
    uint32_t bin1 = sres[0], chi1 = sres[1];
    uint32_t bin2, chi2;
    find_parallel(gH2, 2048, K - chi1, s, sc2, &bin2, &chi2);
    uint32_t t21 = (bin1 << 11) | bin2;
    uint32_t chiTot = chi1 + chi2;  // count of keys with (u>>11) > t21
    if (blockIdx.x == 0 && threadIdx.x == 0) {
        sres[2] = t21; sres[3] = chiTot; sres[4] = K - chiTot;  // m' >= 1
    }
    const uint32_t u_conf = 0xBE800000u;        // map_f(0.25f); low 11 bits are 0
    const uint32_t CONF21 = u_conf >> 11;
    bool tcut = (t21 >= CONF21);                // <=> k-th value >= CONF
    float lsum = 0.f;
    int gid = blockIdx.x * 256 + threadIdx.x;
    int stride = gridDim.x * 256;
    const uint4* s4 = (const uint4*)scores;
    int n4 = n >> 2;
    for (int i = gid; i < n4; i += stride) {
        uint4 uu = s4[i];
#pragma unroll
        for (int j = 0; j < 4; ++j) {
            uint32_t u = (j == 0) ? uu.x : (j == 1) ? uu.y : (j == 2) ? uu.z : uu.w;
            int r = i * 4 + j;
            bool sel = tcut ? ((u >> 11) > t21) : (u >= u_conf);
            if (sel) {
                float4 b = *(const float4*)(pred + (size_t)r * ROWLEN);
                lsum += unmap_f(u) + b.x + b.y + b.z + b.w;
            }
            if (tcut && (u >> 11) == t21) {
                uint32_t pos = atomicAdd(candCnt, 1u);
                if (pos < CANDCAP) candBuf[pos] = make_uint2((uint32_t)r, u);
            }
        }
    }
    for (int r = n4 * 4 + gid; r < n; r += stride) {
        uint32_t u = scores[r];
        bool sel = tcut ? ((u >> 11) > t21) : (u >= u_conf);
        if (sel) {
            float4 b = *(const float4*)(pred + (size_t)r * ROWLEN);
            lsum += unmap_f(u) + b.x + b.y + b.z + b.w;
        }
        if (tcut && (u >> 11) == t21) {
            uint32_t pos = atomicAdd(candCnt, 1u);
            if (pos < CANDCAP) candBuf[pos] = make_uint2((uint32_t)r, u);
        }
    }
    for (int off = 32; off; off >>= 1) lsum += __shfl_down(lsum, off);
    int wid = threadIdx.x >> 6, lane = threadIdx.x & 63;
    if (lane == 0) wsum[wid] = lsum;
    __syncthreads();
    if (threadIdx.x == 0) atomicAdd(out, wsum[0] + wsum[1] + wsum[2] + wsum[3]);
}

// Pass 4 (1 block): refine within the threshold bucket over ~1-2K candidates:
// 11-bit histogram -> bin3 -> exact t_u; sum candidates above; tie-break by lowest index.
__global__ void k_final(const float* __restrict__ pred, const uint32_t* __restrict__ sres,
                        const uint32_t* __restrict__ candCnt, const uint2* __restrict__ candBuf,
                        float* __restrict__ out) {
    __shared__ uint32_t h[2048];
    __shared__ uint32_t s[256];
    __shared__ uint32_t sc2[2];
    __shared__ float wsum[4];
    __shared__ uint32_t tb[1024];
    __shared__ uint32_t tc;
    uint32_t t21 = sres[2];
    const uint32_t u_conf = 0xBE800000u;
    const uint32_t CONF21 = u_conf >> 11;
    if (t21 < CONF21) return;  // selection was pure >=CONF; fully handled in k_select2
    uint32_t mprime = sres[4];
    uint32_t cc = *candCnt;
    if (cc > CANDCAP) cc = CANDCAP;
    int tid = threadIdx.x;
    for (int i = tid; i < 2048; i += 256) h[i] = 0;
    if (tid == 0) tc = 0;
    __syncthreads();
    for (uint32_t i = tid; i < cc; i += 256) atomicAdd(&h[candBuf[i].y & 0x7FFu], 1u);
    __syncthreads();
    uint32_t bin3, chi3;
    find_parallel(h, 2048, mprime, s, sc2, &bin3, &chi3);
    uint32_t t_u = (t21 << 11) | bin3;
    uint32_t mt = mprime - chi3;  // ties to include (>= 1)
    float lsum = 0.f;
    for (uint32_t i = tid; i < cc; i += 256) {
        uint2 c = candBuf[i];
        uint32_t low = c.y & 0x7FFu;
        if (low > bin3) {
            float4 b = *(const float4*)(pred + (size_t)c.x * ROWLEN);
            lsum += unmap_f(c.y) + b.x + b.y + b.z + b.w;
        } else if (low == bin3) {
            uint32_t p = atomicAdd(&tc, 1u);
            if (p < 1024) tb[p] = c.x;
        }
    }
    __syncthreads();
    uint32_t tcnt = tc;
    if (tcnt > 1024) tcnt = 1024;
    if (mt >= tcnt) {
        for (uint32_t i = tid; i < tcnt; i += 256) {
            float4 b = *(const float4*)(pred + (size_t)tb[i] * ROWLEN);
            lsum += b.x + b.y + b.z + b.w;
        }
    } else {
        for (uint32_t i = tid; i < tcnt; i += 256) {
            uint32_t ri = tb[i];
            uint32_t rank = 0;
            for (uint32_t j = 0; j < tcnt; ++j) rank += (tb[j] < ri) ? 1u : 0u;
            if (rank < mt) {
                float4 b = *(const float4*)(pred + (size_t)ri * ROWLEN);
                lsum += b.x + b.y + b.z + b.w;
            }
        }
    }
    for (int off = 32; off; off >>= 1) lsum += __shfl_down(lsum, off);
    int wid = tid >> 6, lane = tid & 63;
    if (lane == 0) wsum[wid] = lsum;
    __syncthreads();
    if (tid == 0)
        atomicAdd(out, wsum[0] + wsum[1] + wsum[2] + wsum[3] + (float)mt * unmap_f(t_u));
}

extern "C" void kernel_launch(void* const* d_in, const int* in_sizes, int n_in,
                              void* d_out, int out_size, void* d_ws, size_t ws_size,
                              hipStream_t stream) {
    const float* pred = (const float*)d_in[0];
    int n = in_sizes[0] / ROWLEN;
    double kd = ceil((double)n * 0.1);
    long kk = (long)kd;
    if (kk < 1) kk = 1;
    if (kk > n) kk = n;
    uint32_t K = (uint32_t)kk;

    uint32_t* ws32 = (uint32_t*)d_ws;
    uint32_t* scores = ws32;         // n words
    uint32_t* gH1 = ws32 + n;        // 1024
    uint32_t* gH2 = gH1 + 1024;      // 2048
    uint32_t* candCnt = gH2 + 2048;  // 16 (1 used)
    uint32_t* sres = candCnt + 16;   // 16
    uint2* candBuf = (uint2*)(sres + 16);  // CANDCAP pairs
    float* out = (float*)d_out;

    // One memset covers gH1 | gH2 (contiguous). candCnt/out zeroed inside k_score_hist.
    hipMemsetAsync(gH1, 0, (1024 + 2048) * sizeof(uint32_t), stream);

    k_score_hist<<<2048, 256, 0, stream>>>(pred, scores, gH1, candCnt, out, n);
    k_hist2f<<<1024, 256, 0, stream>>>(scores, gH1, gH2, sres, n, K);
    k_select2<<<2048, 256, 0, stream>>>(pred, scores, gH2, sres, candCnt, candBuf, out, n, K);
    k_final<<<1, 256, 0, stream>>>(pred, sres, candCnt, candBuf, out);
}